// Round 6
// baseline (473.787 us; speedup 1.0000x reference)
//
#include <hip/hip_runtime.h>
#include <math.h>

#define DD 128
#define HH 16
#define EPSV 1e-5f

static __device__ __forceinline__ ushort f2bf(float f) {
  uint u = __float_as_uint(f);
  u += 0x7FFFu + ((u >> 16) & 1u);
  return (ushort)(u >> 16);
}
static __device__ __forceinline__ float bflo(uint u) { return __uint_as_float(u << 16); }
static __device__ __forceinline__ float bfhi(uint u) { return __uint_as_float(u & 0xFFFF0000u); }

// ---------------- CSR build ----------------

__global__ void k_hist(const int* __restrict__ dst, int* __restrict__ deg, int ecnt) {
  int e = blockIdx.x * blockDim.x + threadIdx.x;
  if (e < ecnt) atomicAdd(&deg[dst[e]], 1);
}

__global__ void k_dinv(const int* __restrict__ deg, float* __restrict__ dinv, int n) {
  int i = blockIdx.x * blockDim.x + threadIdx.x;
  if (i < n) dinv[i] = rsqrtf((float)deg[i] + 2.0f);
}

#define SCAN_T 1024
#define SCAN_I 4

__global__ void k_scan1(const int* __restrict__ deg, int* __restrict__ bsum, int n) {
  __shared__ int sh[SCAN_T];
  int tid = threadIdx.x;
  int base = blockIdx.x * SCAN_T * SCAN_I + tid * SCAN_I;
  int s = 0;
#pragma unroll
  for (int j = 0; j < SCAN_I; ++j) { int i = base + j; if (i < n) s += deg[i]; }
  sh[tid] = s;
  __syncthreads();
  for (int off = SCAN_T / 2; off > 0; off >>= 1) {
    if (tid < off) sh[tid] += sh[tid + off];
    __syncthreads();
  }
  if (tid == 0) bsum[blockIdx.x] = sh[0];
}

__global__ void k_scan2(const int* __restrict__ deg, const int* __restrict__ bsum,
                        int* __restrict__ rowoff, int n) {
  __shared__ int sh[SCAN_T];
  __shared__ int sbase;
  int tid = threadIdx.x;
  int b = blockIdx.x;
  if (tid == 0) { int s = 0; for (int j = 0; j < b; ++j) s += bsum[j]; sbase = s; }
  int base = b * SCAN_T * SCAN_I + tid * SCAN_I;
  int d[SCAN_I]; int ts = 0;
#pragma unroll
  for (int j = 0; j < SCAN_I; ++j) { int i = base + j; d[j] = (i < n) ? deg[i] : 0; ts += d[j]; }
  sh[tid] = ts;
  __syncthreads();
  for (int off = 1; off < SCAN_T; off <<= 1) {
    int v = (tid >= off) ? sh[tid - off] : 0;
    __syncthreads();
    sh[tid] += v;
    __syncthreads();
  }
  int ex = sbase + sh[tid] - ts;
#pragma unroll
  for (int j = 0; j < SCAN_I; ++j) {
    int i = base + j;
    if (i < n) rowoff[i] = ex;
    ex += d[j];
  }
}

__global__ void k_fill(const int* __restrict__ src, const int* __restrict__ dst,
                       const float* __restrict__ dinv, const int* __restrict__ rowoff,
                       int* __restrict__ cursor, int2* __restrict__ csr, int ecnt) {
  int e = blockIdx.x * blockDim.x + threadIdx.x;
  if (e >= ecnt) return;
  int s = src[e], d = dst[e];
  int p = atomicAdd(&cursor[d], 1);
  float nw = dinv[s] * dinv[d];
  csr[rowoff[d] + p] = make_int2(s, __float_as_int(nw));
}

// ---------------- GEMM: C_bf16[nrows,128] = A_f32[nrows,128] @ B[128,128] ----------------

__global__ __launch_bounds__(256) void k_gemm(const float* __restrict__ A,
                                              const float* __restrict__ B,
                                              ushort* __restrict__ C, int nrows) {
  __shared__ float Bs[DD * 64];
  int tid = threadIdx.x;
  int tx = tid & 15, ty = tid >> 4;
  int rowbase = blockIdx.x * 128;
  int c0 = blockIdx.y * 64;
  {
    int kk = tid >> 4;
    int cc = (tid & 15) * 4;
#pragma unroll
    for (int p = 0; p < 8; ++p) {
      int k = p * 16 + kk;
      float4 bv = *reinterpret_cast<const float4*>(&B[k * DD + c0 + cc]);
      *reinterpret_cast<float4*>(&Bs[k * 64 + cc]) = bv;
    }
  }
  __syncthreads();
  float acc[8][4];
#pragma unroll
  for (int i = 0; i < 8; ++i)
#pragma unroll
    for (int j = 0; j < 4; ++j) acc[i][j] = 0.f;
  int rl[8];
#pragma unroll
  for (int i = 0; i < 8; ++i) {
    int r = rowbase + ty * 8 + i;
    rl[i] = (r < nrows) ? r : (nrows - 1);
  }
  const float4* A4 = reinterpret_cast<const float4*>(A);
  for (int kq = 0; kq < 32; ++kq) {
    float4 av[8];
#pragma unroll
    for (int i = 0; i < 8; ++i) av[i] = A4[(size_t)rl[i] * 32 + kq];
#pragma unroll
    for (int j = 0; j < 4; ++j) {
      float4 bv = *reinterpret_cast<const float4*>(&Bs[(kq * 4 + j) * 64 + tx * 4]);
#pragma unroll
      for (int i = 0; i < 8; ++i) {
        float a = (j == 0) ? av[i].x : (j == 1) ? av[i].y : (j == 2) ? av[i].z : av[i].w;
        acc[i][0] = fmaf(a, bv.x, acc[i][0]);
        acc[i][1] = fmaf(a, bv.y, acc[i][1]);
        acc[i][2] = fmaf(a, bv.z, acc[i][2]);
        acc[i][3] = fmaf(a, bv.w, acc[i][3]);
      }
    }
  }
  int cbase = c0 + tx * 4;
#pragma unroll
  for (int i = 0; i < 8; ++i) {
    int r = rowbase + ty * 8 + i;
    if (r < nrows) {
      ushort4 o;
      o.x = f2bf(acc[i][0]); o.y = f2bf(acc[i][1]);
      o.z = f2bf(acc[i][2]); o.w = f2bf(acc[i][3]);
      *reinterpret_cast<ushort4*>(&C[(size_t)r * DD + cbase]) = o;
    }
  }
}

// ---------------- edge accumulate: 2 edges per gather instruction ----------------
// Half-wave (32 lanes) covers one 256B bf16 row; lane owns 4 dims (uint2).
// Lanes 0-31 process even batch slots, lanes 32-63 odd slots -> one gather
// instruction fetches TWO edges (8 lines). Halves summed by caller via
// shfl_xor(,32); self-loop/bias must be added AFTER that combine.

static __device__ __forceinline__ void edge_accum(
    const uint2* __restrict__ xw64, const int2* __restrict__ cs0,
    int rem, uint cl, uint half,
    float& a0, float& a1, float& a2, float& a3) {
  const int2* cs = cs0;
  while (rem >= 16) {  // 8 gather instrs = 16 edges
    int2 c[8];
#pragma unroll
    for (int j = 0; j < 8; ++j) c[j] = cs[2 * j + half];
    uint2 v[8];
#pragma unroll
    for (int j = 0; j < 8; ++j) v[j] = xw64[((uint)c[j].x << 5) + cl];
#pragma unroll
    for (int j = 0; j < 8; ++j) {
      float nw = __int_as_float(c[j].y);
      a0 = fmaf(bflo(v[j].x), nw, a0);
      a1 = fmaf(bfhi(v[j].x), nw, a1);
      a2 = fmaf(bflo(v[j].y), nw, a2);
      a3 = fmaf(bfhi(v[j].y), nw, a3);
    }
    cs += 16; rem -= 16;
  }
  while (rem >= 4) {  // 2 gather instrs = 4 edges
    int2 c[2];
#pragma unroll
    for (int j = 0; j < 2; ++j) c[j] = cs[2 * j + half];
    uint2 v[2];
#pragma unroll
    for (int j = 0; j < 2; ++j) v[j] = xw64[((uint)c[j].x << 5) + cl];
#pragma unroll
    for (int j = 0; j < 2; ++j) {
      float nw = __int_as_float(c[j].y);
      a0 = fmaf(bflo(v[j].x), nw, a0);
      a1 = fmaf(bfhi(v[j].x), nw, a1);
      a2 = fmaf(bflo(v[j].y), nw, a2);
      a3 = fmaf(bfhi(v[j].y), nw, a3);
    }
    cs += 4; rem -= 4;
  }
  if (rem > 0) {  // up to 3 edges, predicated per half
#pragma unroll
    for (int j = 0; j < 2; ++j) {
      int k = 2 * j + (int)half;
      bool act = k < rem;
      int2 c = cs[act ? k : 0];
      float nw = act ? __int_as_float(c.y) : 0.f;
      uint2 v = xw64[((uint)c.x << 5) + cl];
      a0 = fmaf(bflo(v.x), nw, a0);
      a1 = fmaf(bfhi(v.x), nw, a1);
      a2 = fmaf(bflo(v.y), nw, a2);
      a3 = fmaf(bfhi(v.y), nw, a3);
    }
  }
}

// ---------------- agg1: gather + self + bias + LN + ReLU -> fp32 h1 ----------------

__global__ __launch_bounds__(256) void k_agg1(
    const ushort* __restrict__ xw, const int2* __restrict__ csr,
    const int* __restrict__ rowoff, const int* __restrict__ deg,
    const float* __restrict__ dinv, const float* __restrict__ bias,
    const float* __restrict__ gam, const float* __restrict__ bet,
    float* __restrict__ outp, int n) {
  int wv = threadIdx.x >> 6, lane = threadIdx.x & 63;
  int i = blockIdx.x * 4 + wv;
  if (i >= n) return;
  uint half = (uint)lane >> 5, cl = (uint)lane & 31;
  int start = rowoff[i], cnt = deg[i];
  float di = dinv[i];
  const uint2* xw64 = (const uint2*)xw;
  float a0 = 0.f, a1 = 0.f, a2 = 0.f, a3 = 0.f;
  const int2* cs0 = csr + __builtin_amdgcn_readfirstlane(start);
  edge_accum(xw64, cs0, __builtin_amdgcn_readfirstlane(cnt), cl, half, a0, a1, a2, a3);
  // combine halves
  a0 += __shfl_xor(a0, 32);
  a1 += __shfl_xor(a1, 32);
  a2 += __shfl_xor(a2, 32);
  a3 += __shfl_xor(a3, 32);
  // self-loop + bias (after combine!)
  uint2 su = xw64[((uint)i << 5) + cl];
  float sw = 2.f * di * di;
  float4 bv = ((const float4*)bias)[cl];
  a0 = fmaf(bflo(su.x), sw, a0) + bv.x;
  a1 = fmaf(bfhi(su.x), sw, a1) + bv.y;
  a2 = fmaf(bflo(su.y), sw, a2) + bv.z;
  a3 = fmaf(bfhi(su.y), sw, a3) + bv.w;
  // LayerNorm over 128 dims: 5-level reduce within 32-lane half (halves identical)
  float s = a0 + a1 + a2 + a3;
#pragma unroll
  for (int off = 16; off > 0; off >>= 1) s += __shfl_xor(s, off);
  float mu = s * (1.f / DD);
  float c0 = a0 - mu, c1 = a1 - mu, c2 = a2 - mu, c3 = a3 - mu;
  float q = c0 * c0 + c1 * c1 + c2 * c2 + c3 * c3;
#pragma unroll
  for (int off = 16; off > 0; off >>= 1) q += __shfl_xor(q, off);
  float rstd = rsqrtf(q * (1.f / DD) + EPSV);
  float4 gv = ((const float4*)gam)[cl];
  float4 tv = ((const float4*)bet)[cl];
  if (half == 0) {
    float4 o;
    o.x = fmaxf(fmaf(c0 * rstd, gv.x, tv.x), 0.f);
    o.y = fmaxf(fmaf(c1 * rstd, gv.y, tv.y), 0.f);
    o.z = fmaxf(fmaf(c2 * rstd, gv.z, tv.z), 0.f);
    o.w = fmaxf(fmaf(c3 * rstd, gv.w, tv.w), 0.f);
    ((float4*)(outp + (size_t)i * DD))[cl] = o;
  }
}

// ---------------- agg2: gather + LN + SE + residual + ReLU -> fp32 out ----------------

__global__ __launch_bounds__(256) void k_agg2(
    const ushort* __restrict__ xw, const int2* __restrict__ csr,
    const int* __restrict__ rowoff, const int* __restrict__ deg,
    const float* __restrict__ dinv, const float* __restrict__ bias,
    const float* __restrict__ gam, const float* __restrict__ bet,
    const float* __restrict__ Ws, const float* __restrict__ bs,
    const float* __restrict__ We, const float* __restrict__ be,
    const float* __restrict__ xin, float* __restrict__ outp, int n) {
  int wv = threadIdx.x >> 6, lane = threadIdx.x & 63;
  int i = blockIdx.x * 4 + wv;
  if (i >= n) return;
  uint half = (uint)lane >> 5, cl = (uint)lane & 31;
  int start = rowoff[i], cnt = deg[i];
  float di = dinv[i];
  const uint2* xw64 = (const uint2*)xw;
  float a0 = 0.f, a1 = 0.f, a2 = 0.f, a3 = 0.f;
  const int2* cs0 = csr + __builtin_amdgcn_readfirstlane(start);
  edge_accum(xw64, cs0, __builtin_amdgcn_readfirstlane(cnt), cl, half, a0, a1, a2, a3);
  a0 += __shfl_xor(a0, 32);
  a1 += __shfl_xor(a1, 32);
  a2 += __shfl_xor(a2, 32);
  a3 += __shfl_xor(a3, 32);
  uint2 su = xw64[((uint)i << 5) + cl];
  float sw = 2.f * di * di;
  float4 bv = ((const float4*)bias)[cl];
  a0 = fmaf(bflo(su.x), sw, a0) + bv.x;
  a1 = fmaf(bfhi(su.x), sw, a1) + bv.y;
  a2 = fmaf(bflo(su.y), sw, a2) + bv.z;
  a3 = fmaf(bfhi(su.y), sw, a3) + bv.w;
  // LayerNorm
  float s = a0 + a1 + a2 + a3;
#pragma unroll
  for (int off = 16; off > 0; off >>= 1) s += __shfl_xor(s, off);
  float mu = s * (1.f / DD);
  float c0 = a0 - mu, c1 = a1 - mu, c2 = a2 - mu, c3 = a3 - mu;
  float q = c0 * c0 + c1 * c1 + c2 * c2 + c3 * c3;
#pragma unroll
  for (int off = 16; off > 0; off >>= 1) q += __shfl_xor(q, off);
  float rstd = rsqrtf(q * (1.f / DD) + EPSV);
  float4 gv = ((const float4*)gam)[cl];
  float4 tv = ((const float4*)bet)[cl];
  float h0 = fmaf(c0 * rstd, gv.x, tv.x);
  float h1 = fmaf(c1 * rstd, gv.y, tv.y);
  float h2 = fmaf(c2 * rstd, gv.z, tv.z);
  float h3 = fmaf(c3 * rstd, gv.w, tv.w);
  // SE: s16 = relu(h @ Ws + bs); w = sigmoid(s16 @ We + be)
  float pj[HH];
#pragma unroll
  for (int j = 0; j < HH; ++j) pj[j] = 0.f;
#pragma unroll
  for (int k = 0; k < 4; ++k) {
    float hk = (k == 0) ? h0 : (k == 1) ? h1 : (k == 2) ? h2 : h3;
    const float4* wr = (const float4*)&Ws[(4 * cl + k) * HH];
#pragma unroll
    for (int jj = 0; jj < 4; ++jj) {
      float4 w4 = wr[jj];
      pj[4 * jj + 0] = fmaf(hk, w4.x, pj[4 * jj + 0]);
      pj[4 * jj + 1] = fmaf(hk, w4.y, pj[4 * jj + 1]);
      pj[4 * jj + 2] = fmaf(hk, w4.z, pj[4 * jj + 2]);
      pj[4 * jj + 3] = fmaf(hk, w4.w, pj[4 * jj + 3]);
    }
  }
#pragma unroll
  for (int off = 16; off > 0; off >>= 1) {
#pragma unroll
    for (int j = 0; j < HH; ++j) pj[j] += __shfl_xor(pj[j], off);
  }
  float4 bev = ((const float4*)be)[cl];
  float w0 = bev.x, w1 = bev.y, w2 = bev.z, w3 = bev.w;
#pragma unroll
  for (int j = 0; j < HH; ++j) {
    float sj = fmaxf(pj[j] + bs[j], 0.f);
    float4 wev = ((const float4*)(We + j * DD))[cl];
    w0 = fmaf(sj, wev.x, w0);
    w1 = fmaf(sj, wev.y, w1);
    w2 = fmaf(sj, wev.z, w2);
    w3 = fmaf(sj, wev.w, w3);
  }
  if (half == 0) {
    float g0 = 1.f / (1.f + __expf(-w0));
    float g1 = 1.f / (1.f + __expf(-w1));
    float g2 = 1.f / (1.f + __expf(-w2));
    float g3 = 1.f / (1.f + __expf(-w3));
    float4 xr = ((const float4*)(xin + (size_t)i * DD))[cl];
    float4 o;
    o.x = fmaxf(fmaf(h0, g0, xr.x), 0.f);
    o.y = fmaxf(fmaf(h1, g1, xr.y), 0.f);
    o.z = fmaxf(fmaf(h2, g2, xr.z), 0.f);
    o.w = fmaxf(fmaf(h3, g3, xr.w), 0.f);
    ((float4*)(outp + (size_t)i * DD))[cl] = o;
  }
}

// ---------------- launcher ----------------

extern "C" void kernel_launch(void* const* d_in, const int* in_sizes, int n_in,
                              void* d_out, int out_size, void* d_ws, size_t ws_size,
                              hipStream_t stream) {
  const float* x   = (const float*)d_in[0];
  const int*   ei  = (const int*)d_in[1];
  const float* W1  = (const float*)d_in[2];
  const float* b1  = (const float*)d_in[3];
  const float* g1  = (const float*)d_in[4];
  const float* be1 = (const float*)d_in[5];
  const float* W2  = (const float*)d_in[6];
  const float* b2  = (const float*)d_in[7];
  const float* g2  = (const float*)d_in[8];
  const float* be2 = (const float*)d_in[9];
  const float* Ws  = (const float*)d_in[10];
  const float* bs  = (const float*)d_in[11];
  const float* We  = (const float*)d_in[12];
  const float* bee = (const float*)d_in[13];
  float* outp = (float*)d_out;

  int n    = in_sizes[0] / DD;
  int ecnt = in_sizes[1] / 2;
  const int* src = ei;
  const int* dst = ei + ecnt;

  char* w = (char*)d_ws;
  ushort* xw    = (ushort*)w; w += (size_t)n * DD * 2;
  float*  h1    = (float*)w;  w += (size_t)n * DD * 4;
  int*    deg   = (int*)w;    w += (size_t)n * 4;
  int*    cursor= (int*)w;    w += (size_t)n * 4;  // adjacent to deg (one memset)
  int*    rowoff= (int*)w;    w += (size_t)n * 4;
  float*  dinv  = (float*)w;  w += (size_t)n * 4;
  int*    bsum  = (int*)w;    w += 64 * 4;
  int2*   csr   = (int2*)w;   w += (size_t)ecnt * 8;

  hipMemsetAsync(deg, 0, (size_t)n * 8, stream);  // deg + cursor

  const int TB = 256;
  int eb = (ecnt + TB - 1) / TB;
  int nbk = (n + TB - 1) / TB;
  k_hist<<<eb, TB, 0, stream>>>(dst, deg, ecnt);
  k_dinv<<<nbk, TB, 0, stream>>>(deg, dinv, n);
  int nb = (n + SCAN_T * SCAN_I - 1) / (SCAN_T * SCAN_I);
  k_scan1<<<nb, SCAN_T, 0, stream>>>(deg, bsum, n);
  k_scan2<<<nb, SCAN_T, 0, stream>>>(deg, bsum, rowoff, n);
  k_fill<<<eb, TB, 0, stream>>>(src, dst, dinv, rowoff, cursor, csr, ecnt);

  dim3 gg((n + 127) / 128, 2);
  int nb4 = (n + 3) / 4;
  k_gemm<<<gg, 256, 0, stream>>>(x, W1, xw, n);
  k_agg1<<<nb4, 256, 0, stream>>>(xw, csr, rowoff, deg, dinv, b1, g1, be1, h1, n);
  k_gemm<<<gg, 256, 0, stream>>>(h1, W2, xw, n);
  k_agg2<<<nb4, 256, 0, stream>>>(xw, csr, rowoff, deg, dinv, b2, g2, be2,
                                  Ws, bs, We, bee, x, outp, n);
}